// Round 11
// baseline (248.195 us; speedup 1.0000x reference)
//
#include <hip/hip_runtime.h>

// NNConvCritic on MI355X (gfx950).
// R21: occupancy push — the one untried documented lever. R20 reproduced
// the consolidated best (237.0us; edge 103us; 3 waves/SIMD from ~136
// unified regs). This round shaves ~10 regs then retries (256,4):
// (a) merged staging regs: xstg/estg -> one bitcast u32x4 stg;
//     srcg,src2/dstg,dst2 -> one idxg,idx2 pair (disjoint wave roles,
//     uniform allocation pays the max) [-6];
// (b) bw1 -> LDS, DOUBLE-BUFFERED copy read via [cur] so LICM cannot
//     hoist it back into registers; one ds_read_b128/iter [-4];
// (c) __launch_bounds__(256, 4): 128-reg budget, target 4 waves/SIMD.
// ABORT CRITERION (R14 spill signature): WRITE_SIZE >30MB or edge
// >130us -> spilled -> next round reverts to R20 exactly.
// LESSON (R19): fewer instructions != faster; minimal diff elsewhere.
// LESSON (R18): fp atomicAdd => CAS retry loop. int fixed-point only.
// LESSON (R12/R13/R17): edge load latency is NOT the stall.
// LESSON (R16): device-scope atomics+threadfence poison streaming setup.
// LESSON (R6/R9/R14): VGPR budget < live set -> scratch spill.
// Pipeline: memset -> setup -> mid -> edge -> critic.

#define E_EDGES   800000
#define N_NODES   50000
#define G_GRAPHS  64
#define EDGE_GRID 3072      // 4-wave blocks
#define NGROUPS   50000     // E/16
#define GSTRIDE   3072      // group streams
#define NSUP      256       // super-slices for the int flush (12 blocks ea)
#define STAT_GRID 512
#define QSCALE    131072.0f // 2^17
#define QINV      (1.0f / 131072.0f)

typedef _Float16 f16x2 __attribute__((ext_vector_type(2)));
typedef _Float16 f16x8 __attribute__((ext_vector_type(8)));
typedef __fp16   fp16x2 __attribute__((ext_vector_type(2)));
typedef float    f32x4 __attribute__((ext_vector_type(4)));
typedef unsigned u32x4 __attribute__((ext_vector_type(4)));

union H2U { f16x2 h; unsigned u; };
union F8U { f16x8 v; f16x2 h2[4]; u32x4 u4; };

__device__ __forceinline__ f16x2 pkrtz(float a, float b) {
  fp16x2 r = __builtin_amdgcn_cvt_pkrtz(a, b);
  return __builtin_bit_cast(f16x2, r);
}

// round-nearest-even (x * 2^17) for |x*2^17| < 2^22, 2 VALU ops
__device__ __forceinline__ int q17(float x) {
  float r = __builtin_fmaf(x, QSCALE, 12582912.0f);  // 1.5 * 2^23
  return __builtin_bit_cast(int, r) - 0x4B400000;
}

// ---------------------------------------------------------------------------
// setup: blocks [0,512) stats | [512,582) prep | [582,...) xconv.
// ---------------------------------------------------------------------------
__global__ __launch_bounds__(256) void setup_kernel(
    const float* __restrict__ W2, const float* __restrict__ b2,
    const float* __restrict__ W1, const float* __restrict__ x,
    const float* __restrict__ ea, unsigned* __restrict__ Bbuf,
    unsigned* __restrict__ Bw1, unsigned* __restrict__ xh,
    float* __restrict__ gstatsT)
{
  __shared__ float red[4][272];
  const int b = blockIdx.x, tid = threadIdx.x;
  if (b < STAT_GRID) {
    int lane = tid & 63, wave = tid >> 6;
    int nl = lane & 15, q = lane >> 4;
    int gw = b * 4 + wave;
    f32x4 acc = (f32x4){0.f, 0.f, 0.f, 0.f};
    float ms = 0.f;
    for (int c0 = gw; c0 < E_EDGES / 32; c0 += STAT_GRID * 4) {
      const float* p = ea + (size_t)(c0 * 32 + q * 8) * 16 + nl;
      float v0 = p[0],  v1 = p[16], v2 = p[32], v3 = p[48];
      float v4 = p[64], v5 = p[80], v6 = p[96], v7 = p[112];
      ms += (v0 + v1) + (v2 + v3) + (v4 + v5) + (v6 + v7);
      F8U av;
      av.h2[0] = pkrtz(v0, v1); av.h2[1] = pkrtz(v2, v3);
      av.h2[2] = pkrtz(v4, v5); av.h2[3] = pkrtz(v6, v7);
      acc = __builtin_amdgcn_mfma_f32_16x16x32_f16(av.v, av.v, acc, 0, 0, 0);
    }
    ms += __shfl_xor(ms, 16, 64);
    ms += __shfl_xor(ms, 32, 64);
#pragma unroll
    for (int r = 0; r < 4; ++r) red[wave][(q * 4 + r) * 16 + nl] = acc[r];
    if (q == 0) red[wave][256 + nl] = ms;
    __syncthreads();
    for (int v = tid; v < 272; v += 256)
      gstatsT[(size_t)v * STAT_GRID + b] =
          red[0][v] + red[1][v] + red[2][v] + red[3][v];
  } else if (b < STAT_GRID + 70) {
    int idx = (b - STAT_GRID) * 256 + tid;  // [0, 17920) = 16896 + 1024
    if (idx < 33 * 512) {
      int r = idx & 3, lane = (idx >> 2) & 63, nt = (idx >> 8) & 1,
          s = idx >> 9;
      int q = lane >> 4, nl = lane & 15, n = nt * 16 + nl;
      float v0 = 0.f, v1 = 0.f;
      if (n < 20) {
        if (s < 32) {
          int K0 = s * 32 + q * 8 + 2 * r;
          v0 = W2[(K0 >> 4) * 320 + (K0 & 15) * 20 + n];
          v1 = W2[((K0 + 1) >> 4) * 320 + ((K0 + 1) & 15) * 20 + n];
        } else if (q < 2) {
          int i0 = q * 8 + 2 * r;
          v0 = b2[i0 * 20 + n];
          v1 = b2[(i0 + 1) * 20 + n];
        }
      }
      H2U pk; pk.h = pkrtz(v0, v1);
      Bbuf[idx] = pk.u;
    } else {
      int idx2 = idx - 33 * 512;  // [0,1024)
      int r = idx2 & 3, lane = (idx2 >> 2) & 63, nt = idx2 >> 8;
      int q = lane >> 4, nl = lane & 15, n = nt * 16 + nl;
      int k0 = q * 8 + 2 * r;
      float v0 = (k0 < 16)     ? W1[k0 * 64 + n]       : 0.f;
      float v1 = (k0 + 1 < 16) ? W1[(k0 + 1) * 64 + n] : 0.f;
      H2U pk; pk.h = pkrtz(v0, v1);
      Bw1[idx2] = pk.u;
    }
  } else {
    int i = (b - STAT_GRID - 70) * 256 + tid;
    if (i < N_NODES * 8) {
      H2U pk; pk.h = pkrtz(x[2 * i], x[2 * i + 1]);
      xh[i] = pk.u;
    }
  }
}

// ---------------------------------------------------------------------------
// mid: block 64 = stats reduce + BN scale/shift; blocks 0..63 = sumx/cnt.
// Stats reduce: thread-per-row, 4 independent accumulators — keeps 100s
// of loads in flight (R12's wave-per-row shfl chain was 8x slower).
// ---------------------------------------------------------------------------
__global__ __launch_bounds__(256) void mid_kernel(
    const float* __restrict__ gstatsT, const float* __restrict__ W1,
    const float* __restrict__ b1, const float* __restrict__ gamma,
    const float* __restrict__ beta, const float* __restrict__ x,
    const int* __restrict__ batch, float* __restrict__ sc,
    float* __restrict__ sh, float* __restrict__ sumx,
    float* __restrict__ cntf)
{
  const int t = threadIdx.x;
  if (blockIdx.x == G_GRAPHS) {
    __shared__ float S[272];
    for (int v = t; v < 272; v += 256) {
      const float* p = gstatsT + (size_t)v * STAT_GRID;
      float s0 = 0.f, s1 = 0.f, s2 = 0.f, s3 = 0.f;
      for (int bb = 0; bb < STAT_GRID; bb += 4) {
        s0 += p[bb]; s1 += p[bb + 1]; s2 += p[bb + 2]; s3 += p[bb + 3];
      }
      S[v] = (s0 + s1) + (s2 + s3);
    }
    __syncthreads();
    if (t < 64) {
      float w[16];
#pragma unroll
      for (int j = 0; j < 16; ++j) w[j] = W1[j * 64 + t];
      const float invE = 1.0f / (float)E_EDGES;
      float mw = 0.f;
#pragma unroll
      for (int j = 0; j < 16; ++j) mw += S[256 + j] * w[j];
      mw *= invE;
      float qf = 0.f;
      for (int j = 0; j < 16; ++j) {
        float tt = 0.f;
#pragma unroll
        for (int j2 = 0; j2 < 16; ++j2) tt += S[j * 16 + j2] * w[j2];
        qf += w[j] * tt;
      }
      qf *= invE;
      float b = b1[t];
      float meanH = mw + b;
      float eh2 = qf + 2.f * b * mw + b * b;
      float var = eh2 - meanH * meanH;
      float s = gamma[t] * rsqrtf(var + 1e-5f);
      sc[t] = s;
      sh[t] = beta[t] + (b - meanH) * s;
    }
  } else {
    int g = blockIdx.x;
    __shared__ int se[2];
    if (t < 2) {
      int key = g + t;
      int lo = 0, hi = N_NODES;
      while (lo < hi) {
        int mid = (lo + hi) >> 1;
        if (batch[mid] < key) lo = mid + 1; else hi = mid;
      }
      se[t] = lo;
    }
    __syncthreads();
    int start = se[0], end = se[1];
    int c = t & 15, rr = t >> 4;
    float s = 0.f;
    for (int n = start + rr; n < end; n += 16) s += x[(size_t)n * 16 + c];
    __shared__ float red[256];
    red[t] = s;
    __syncthreads();
#pragma unroll
    for (int st = 128; st >= 16; st >>= 1) {
      if (t < st) red[t] += red[t + st];
      __syncthreads();
    }
    if (t < 16) sumx[g * 16 + t] = red[t];
    if (t == 0) cntf[g] = (float)(end - start);
  }
}

// ---------------------------------------------------------------------------
// edge_kernel: R20 structure with a ~10-reg shave for (256,4):
// merged staging regs (stg / idxg,idx2) + bw1 in double-buffered LDS
// (read via [cur] each iteration -> not hoistable). Otherwise identical:
// wave w = kq, LDS-staged group data (T14 depth-1), private bb B-table,
// h-quarter MFMA deferred hh write, 16(+2)-MFMA K-loop, 4 acc chains,
// q17 int ds atomics into shared gacc, one barrier/iter, int flush.
// ---------------------------------------------------------------------------
__global__ __launch_bounds__(256, 4) void edge_kernel(
    const unsigned* __restrict__ xh, const float* __restrict__ ea,
    const int* __restrict__ ei, const int* __restrict__ batch,
    const float* __restrict__ sc, const float* __restrict__ sh,
    const unsigned* __restrict__ Bbuf, const unsigned* __restrict__ Bw1v,
    int* __restrict__ gpartI)
{
  __shared__ unsigned hh[4][640];   // per-wave h dbuf [w][buf*320 + c*20 + m]
  __shared__ int gacc[1280];        // shared per-graph fixed-point sums
  __shared__ float sEA[2][256];     // [buf][e*16 + f] raw f32 edge_attr
  __shared__ unsigned sXH[2][128];  // [buf][(n*2+half)*4 + word] 32x16B
  __shared__ int sGE[2][16];        // [buf][e] raw batch value
  __shared__ unsigned sBX[2][256];  // bx table (kq==3): [nt][lane*4+word]
  __shared__ unsigned sBW1[2][1024];// bw1, 2 copies read via [cur] (no LICM)

  const int tid = threadIdx.x;
  const int w = tid >> 6;           // wave id == kq
  const int lane = tid & 63;
  const int nl = lane & 15, q = lane >> 4;
  const int qh = q & 1;
  const int kq = w;

  for (int v = tid; v < 1280; v += 256) gacc[v] = 0;

  // persistent B fragments (this wave's K-quarter)
  F8U bb[8][2];
#pragma unroll
  for (int sl = 0; sl < 8; ++sl)
#pragma unroll
    for (int nt = 0; nt < 2; ++nt)
      bb[sl][nt].u4 =
          ((const u32x4*)Bbuf)[((kq * 8 + sl) * 2 + nt) * 64 + lane];
  {
    u32x4 bwv = ((const u32x4*)Bw1v)[kq * 64 + lane];
    *(u32x4*)&sBW1[0][w * 256 + lane * 4] = bwv;
    *(u32x4*)&sBW1[1][w * 256 + lane * 4] = bwv;
  }
  const float scv = sc[kq * 16 + nl];
  const float shv = sh[kq * 16 + nl];
  const int hrb = (q >> 1) * 20 + nl;  // h read: c = 2sl+(q>>1), m = nl

  if (w == 3) {  // bx -> LDS
    u32x4 b0 = ((const u32x4*)Bbuf)[64 * 64 + lane];
    u32x4 b1 = ((const u32x4*)Bbuf)[65 * 64 + lane];
    *(u32x4*)&sBX[0][lane * 4] = b0;
    *(u32x4*)&sBX[1][lane * 4] = b1;
  }

  const int* srcp = ei;
  const int* dstp = ei + E_EDGES;
  int g = blockIdx.x;
  const int g1 = g + GSTRIDE;          // < NGROUPS always (max 6143)
  int idxg = 0;                        // w0: src idx / w2: dst idx for g+1

  // ---- prologue: h(g0); stage xh/batch(g0)->buf0, ea(g1)->buf0 ----
  {
    const int base0 = g * 16;
    f32x4 eA = (f32x4){0.f, 0.f, 0.f, 0.f}, eB = eA;
    if (q < 2) {
      const float* p = ea + (size_t)(base0 + nl) * 16 + q * 8;
      eA = *(const f32x4*)p;
      eB = *(const f32x4*)(p + 4);
    }
    F8U aEA;
    if (q < 2) {
      aEA.h2[0] = pkrtz(eA[0], eA[1]); aEA.h2[1] = pkrtz(eA[2], eA[3]);
      aEA.h2[2] = pkrtz(eB[0], eB[1]); aEA.h2[3] = pkrtz(eB[2], eB[3]);
    } else {
      aEA.u4 = (u32x4){0u, 0u, 0u, 0u};
    }
    F8U bwv; bwv.u4 = *(const u32x4*)&sBW1[0][w * 256 + lane * 4];
    f32x4 hD = __builtin_amdgcn_mfma_f32_16x16x32_f16(
        aEA.v, bwv.v, (f32x4){0.f, 0.f, 0.f, 0.f}, 0, 0, 0);
    u32x4 hwv;
#pragma unroll
    for (int r = 0; r < 4; ++r) {
      float h = fmaxf(hD[r] * scv + shv, 0.f);
      H2U pk; pk.h = pkrtz(h, h);
      hwv[r] = pk.u;
    }
    *(u32x4*)&hh[w][nl * 20 + q * 4] = hwv;

    if (w == 0) {
      if (lane < 32) {
        int s0 = srcp[base0 + (lane >> 1)];
        u32x4 xv = ((const u32x4*)xh)[s0 * 2 + (lane & 1)];
        *(u32x4*)&sXH[0][lane * 4] = xv;
        idxg = srcp[g1 * 16 + (lane >> 1)];
      }
    } else if (w == 2) {
      if (lane < 16) {
        int d0 = dstp[base0 + lane];
        sGE[0][lane] = batch[d0];
        idxg = dstp[g1 * 16 + lane];
      }
    } else if (w == 1) {
      f32x4 ev = *(const f32x4*)(ea + (size_t)g1 * 256 + lane * 4);
      *(f32x4*)&sEA[0][lane * 4] = ev;
    }
  }
  __syncthreads();

  int cur = 0;
  while (g < NGROUPS) {
    const int gn = g + GSTRIDE, g2 = gn + GSTRIDE;
    const bool hv = (gn < NGROUPS);

    // ---- stage issue (merged regs; LDS writes deferred past K-loop) ----
    u32x4 stg;                         // w0: xh data | w1: ea data (bitcast)
    int gestg = 0, idx2 = 0;
    if (w == 0) {
      if (lane < 32) {
        if (hv) stg = ((const u32x4*)xh)[idxg * 2 + (lane & 1)];
        if (g2 < NGROUPS) idx2 = srcp[g2 * 16 + (lane >> 1)];
      }
    } else if (w == 2) {
      if (lane < 16) {
        if (hv) gestg = batch[idxg];
        if (g2 < NGROUPS) idx2 = dstp[g2 * 16 + lane];
      }
    } else if (w == 1) {
      if (g2 < NGROUPS)
        stg = *(const u32x4*)(ea + (size_t)g2 * 256 + lane * 4);
    }

    // ---- compute reads (all from LDS staged last iteration) ----
    F8U xcur;
    xcur.u4 = *(const u32x4*)&sXH[cur][(nl * 2 + qh) * 4];
    const int ge0 = sGE[cur][q * 4 + 0] * 20;
    const int ge1 = sGE[cur][q * 4 + 1] * 20;
    const int ge2v = sGE[cur][q * 4 + 2] * 20;
    const int ge3 = sGE[cur][q * 4 + 3] * 20;
    unsigned hu[8];
#pragma unroll
    for (int sl = 0; sl < 8; ++sl) hu[sl] = hh[w][cur * 320 + hrb + sl * 40];

    // ---- h(g+1) MFMA from sEA (bw1 from LDS[cur]; write deferred) ----
    f32x4 hDn = (f32x4){0.f, 0.f, 0.f, 0.f};
    if (hv) {
      F8U aEA;
      if (q < 2) {
        f32x4 eA = *(const f32x4*)&sEA[cur][nl * 16 + q * 8];
        f32x4 eB = *(const f32x4*)&sEA[cur][nl * 16 + q * 8 + 4];
        aEA.h2[0] = pkrtz(eA[0], eA[1]); aEA.h2[1] = pkrtz(eA[2], eA[3]);
        aEA.h2[2] = pkrtz(eB[0], eB[1]); aEA.h2[3] = pkrtz(eB[2], eB[3]);
      } else {
        aEA.u4 = (u32x4){0u, 0u, 0u, 0u};
      }
      F8U bwv; bwv.u4 = *(const u32x4*)&sBW1[cur][w * 256 + lane * 4];
      hDn = __builtin_amdgcn_mfma_f32_16x16x32_f16(
          aEA.v, bwv.v, (f32x4){0.f, 0.f, 0.f, 0.f}, 0, 0, 0);
    }

    // ---- K-loop: A[m][k] = h[m][c] * x[m][i], 4 independent chains ----
    f32x4 a00 = (f32x4){0.f, 0.f, 0.f, 0.f};
    f32x4 a01 = a00, a10 = a00, a11 = a00;
#pragma unroll
    for (int sl = 0; sl < 8; sl += 2) {
      H2U u0; u0.u = hu[sl];
      H2U u1; u1.u = hu[sl + 1];
      F8U av0, av1;
      av0.h2[0] = u0.h * xcur.h2[0];
      av0.h2[1] = u0.h * xcur.h2[1];
      av0.h2[2] = u0.h * xcur.h2[2];
      av0.h2[3] = u0.h * xcur.h2[3];
      av1.h2[0] = u1.h * xcur.h2[0];
      av1.h2[1] = u1.h * xcur.h2[1];
      av1.h2[2] = u1.h * xcur.h2[2];
      av1.h2[3] = u1.h * xcur.h2[3];
      a00 = __builtin_amdgcn_mfma_f32_16x16x32_f16(av0.v, bb[sl][0].v, a00,
                                                   0, 0, 0);
      a10 = __builtin_amdgcn_mfma_f32_16x16x32_f16(av0.v, bb[sl][1].v, a10,
                                                   0, 0, 0);
      a01 = __builtin_amdgcn_mfma_f32_16x16x32_f16(av1.v, bb[sl + 1][0].v,
                                                   a01, 0, 0, 0);
      a11 = __builtin_amdgcn_mfma_f32_16x16x32_f16(av1.v, bb[sl + 1][1].v,
                                                   a11, 0, 0, 0);
    }
    if (kq == 3) {   // b2 extra K-step: A = x, B = bx from LDS
      F8U bxa, bxb;
      bxa.u4 = *(const u32x4*)&sBX[0][lane * 4];
      bxb.u4 = *(const u32x4*)&sBX[1][lane * 4];
      F8U av;
      if (q < 2) av = xcur;
      else       av.u4 = (u32x4){0u, 0u, 0u, 0u};
      a00 = __builtin_amdgcn_mfma_f32_16x16x32_f16(av.v, bxa.v, a00,
                                                   0, 0, 0);
      a10 = __builtin_amdgcn_mfma_f32_16x16x32_f16(av.v, bxb.v, a10,
                                                   0, 0, 0);
    }
    const f32x4 acc0 = a00 + a01;
    const f32x4 acc1 = a10 + a11;

    // ---- deferred writes: hh(g+1) + staging (loads had K-loop cover) ----
    if (hv) {
      u32x4 hwv;
#pragma unroll
      for (int r = 0; r < 4; ++r) {
        float h = fmaxf(hDn[r] * scv + shv, 0.f);
        H2U pk; pk.h = pkrtz(h, h);
        hwv[r] = pk.u;
      }
      *(u32x4*)&hh[w][(cur ^ 1) * 320 + nl * 20 + q * 4] = hwv;
    }
    if (w == 0) {
      if (lane < 32 && hv) *(u32x4*)&sXH[cur ^ 1][lane * 4] = stg;
    } else if (w == 2) {
      if (lane < 16 && hv) sGE[cur ^ 1][lane] = gestg;
    } else if (w == 1) {
      if (g2 < NGROUPS) *(u32x4*)&sEA[cur ^ 1][lane * 4] = stg;
    }

    // ---- fixed-point partials into shared gacc (native ds atomics) ----
    {
      atomicAdd(&gacc[ge0 + nl], q17(acc0[0]));
      if (nl < 4) atomicAdd(&gacc[ge0 + 16 + nl], q17(acc1[0]));
      atomicAdd(&gacc[ge1 + nl], q17(acc0[1]));
      if (nl < 4) atomicAdd(&gacc[ge1 + 16 + nl], q17(acc1[1]));
      atomicAdd(&gacc[ge2v + nl], q17(acc0[2]));
      if (nl < 4) atomicAdd(&gacc[ge2v + 16 + nl], q17(acc1[2]));
      atomicAdd(&gacc[ge3 + nl], q17(acc0[3]));
      if (nl < 4) atomicAdd(&gacc[ge3 + 16 + nl], q17(acc1[3]));
    }

    __syncthreads();
    g = gn; cur ^= 1;
    idxg = idx2;
  }

  // ---- flush: global int atomics into super-slice (12 blocks/slice) ----
  const int ssup = blockIdx.x & (NSUP - 1);
  for (int v = tid; v < 1280; v += 256) {
    int gg = v / 20, o = v - gg * 20;
    atomicAdd(&gpartI[(gg * NSUP + ssup) * 20 + o], gacc[v]);
  }
}

// ---------------------------------------------------------------------------
// critic: block per graph. Exact int reduce of 256 super-slices; pooled =
// (msgsum + sumx@root_w + cnt*bias)/max(cnt,1); 2-layer MLP.
// ---------------------------------------------------------------------------
__global__ __launch_bounds__(256) void critic_kernel(
    const int* __restrict__ gpartI, const float* __restrict__ sumx,
    const float* __restrict__ cntf, const float* __restrict__ root_w,
    const float* __restrict__ bias, const float* __restrict__ a,
    const float* __restrict__ Wc1, const float* __restrict__ bc1,
    const float* __restrict__ Wc2, const float* __restrict__ bc2,
    float* __restrict__ out)
{
  int g = blockIdx.x, t = threadIdx.x;
  __shared__ int part[240];
  __shared__ float pooled[20];
  if (t < 240) {
    int col = t % 20, r = t / 20;  // 12 slice groups
    int s = 0;
    const int* gp = gpartI + (size_t)g * NSUP * 20;
    for (int sl = r; sl < NSUP; sl += 12) s += gp[sl * 20 + col];
    part[t] = s;
  }
  __syncthreads();
  if (t < 20) {
    int si = 0;
#pragma unroll
    for (int r = 0; r < 12; ++r) si += part[r * 20 + t];
    float s = (float)si * QINV;
    float cnt = cntf[g];
    float base = bias[t] * cnt;
#pragma unroll
    for (int i = 0; i < 16; ++i) base += sumx[g * 16 + i] * root_w[i * 20 + t];
    pooled[t] = (s + base) / fmaxf(cnt, 1.f);
  }
  __syncthreads();
  float z = bc1[t];
#pragma unroll
  for (int j = 0; j < 20; ++j) z += pooled[j] * Wc1[j * 256 + t];
#pragma unroll
  for (int j = 0; j < 8; ++j) z += a[g * 8 + j] * Wc1[(20 + j) * 256 + t];
  z = fmaxf(z, 0.f);
  float pr = z * Wc2[t];
#pragma unroll
  for (int off = 32; off >= 1; off >>= 1) pr += __shfl_down(pr, off, 64);
  __shared__ float red[4];
  if ((t & 63) == 0) red[t >> 6] = pr;
  __syncthreads();
  if (t == 0) out[g] = red[0] + red[1] + red[2] + red[3] + bc2[0];
}

// ---------------------------------------------------------------------------
extern "C" void kernel_launch(void* const* d_in, const int* in_sizes, int n_in,
                              void* d_out, int out_size, void* d_ws,
                              size_t ws_size, hipStream_t stream) {
  const float* x         = (const float*)d_in[0];
  const float* edge_attr = (const float*)d_in[1];
  const float* a         = (const float*)d_in[2];
  const int*   ei        = (const int*)d_in[3];
  const int*   batch     = (const int*)d_in[4];
  const float* W1        = (const float*)d_in[5];
  const float* b1        = (const float*)d_in[6];
  const float* gamma     = (const float*)d_in[7];
  const float* beta      = (const float*)d_in[8];
  const float* W2        = (const float*)d_in[9];
  const float* b2        = (const float*)d_in[10];
  const float* root_w    = (const float*)d_in[11];
  const float* bias      = (const float*)d_in[12];
  const float* Wc1       = (const float*)d_in[13];
  const float* bc1       = (const float*)d_in[14];
  const float* Wc2       = (const float*)d_in[15];
  const float* bc2       = (const float*)d_in[16];
  float* out = (float*)d_out;

  // ws layout (floats) — gpartI zeroed via memset, rest fully written
  float* wsf     = (float*)d_ws;
  float* sc      = wsf;                 // 64
  float* sh      = wsf + 64;            // 64
  float* sumx    = wsf + 128;           // 1024
  float* cntf    = wsf + 1152;          // 64
  unsigned* Bw1  = (unsigned*)(wsf + 1216);   // 1024 u32
  unsigned* Bbuf = (unsigned*)(wsf + 2240);   // 16896 u32
  float* gstatsT = wsf + 19136;         // 272*512 = 139264
  unsigned* xhp  = (unsigned*)(wsf + 158400); // N*8 = 400000 u32
  int* gpartI    = (int*)(wsf + 558400);      // 64*256*20 = 327680 ints

  (void)hipMemsetAsync(gpartI, 0, (size_t)G_GRAPHS * NSUP * 20 * sizeof(int),
                       stream);

  const int XCONV_BLOCKS = (N_NODES * 8 + 255) / 256;  // 1563
  setup_kernel<<<STAT_GRID + 70 + XCONV_BLOCKS, 256, 0, stream>>>(
      W2, b2, W1, x, edge_attr, Bbuf, Bw1, xhp, gstatsT);
  mid_kernel<<<G_GRAPHS + 1, 256, 0, stream>>>(gstatsT, W1, b1, gamma, beta,
                                               x, batch, sc, sh, sumx, cntf);
  edge_kernel<<<EDGE_GRID, 256, 0, stream>>>(xhp, edge_attr, ei, batch, sc,
                                             sh, Bbuf, Bw1, gpartI);
  critic_kernel<<<G_GRAPHS, 256, 0, stream>>>(gpartI, sumx, cntf, root_w,
                                              bias, a, Wc1, bc1, Wc2, bc2,
                                              out);
}

// Round 12
// 237.245 us; speedup vs baseline: 1.0462x; 1.0462x over previous
//
#include <hip/hip_runtime.h>

// NNConvCritic on MI355X (gfx950).
// R22: FINAL — byte-exact revert to R20 (237.0us, best of session;
// reproduced twice: 238.4 R15, 237.0 R20). R21's (256,4) occupancy push
// tripped its pre-committed abort criterion: WRITE 19.2->31.3MB,
// FETCH +6MB (scratch), VGPR_Count=64 (budget floor) -> mild spill;
// occupancy rose 31->41% but scratch round-trips cost more (edge 110us).
// STRUCTURAL CEILING: per-wave K-quarter B-table (64 AGPR) + pipeline
// state ~= 136 unified regs; 136x4 > 512-reg file -> 3 waves/SIMD is the
// hard occupancy limit of this decomposition. At 3 waves/SIMD, every
// perturbation direction tested loses:
//   latency-hiding x3 (R12/R13/R17), fusion (R16), fp atomics (R18),
//   instruction diet x2 (R19), 4-waves x2 (R14 budget-128 spill,
//   R21 shaved-128 spill). Occupancy-merge R14->R15 was the one win.
// LESSON (R21): even a shaved live set doesn't fit 128; (256,3) final.
// LESSON (R18): fp atomicAdd => CAS retry loop. int fixed-point only.
// LESSON (R16): device-scope atomics+threadfence poison streaming setup.
// LESSON (R12): single-block reduces need MLP, not coalescing.
// Pipeline: memset -> setup -> mid -> edge -> critic.

#define E_EDGES   800000
#define N_NODES   50000
#define G_GRAPHS  64
#define EDGE_GRID 3072      // 4-wave blocks
#define NGROUPS   50000     // E/16
#define GSTRIDE   3072      // group streams
#define NSUP      256       // super-slices for the int flush (12 blocks ea)
#define STAT_GRID 512
#define QSCALE    131072.0f // 2^17
#define QINV      (1.0f / 131072.0f)

typedef _Float16 f16x2 __attribute__((ext_vector_type(2)));
typedef _Float16 f16x8 __attribute__((ext_vector_type(8)));
typedef __fp16   fp16x2 __attribute__((ext_vector_type(2)));
typedef float    f32x4 __attribute__((ext_vector_type(4)));
typedef unsigned u32x4 __attribute__((ext_vector_type(4)));

union H2U { f16x2 h; unsigned u; };
union F8U { f16x8 v; f16x2 h2[4]; u32x4 u4; };

__device__ __forceinline__ f16x2 pkrtz(float a, float b) {
  fp16x2 r = __builtin_amdgcn_cvt_pkrtz(a, b);
  return __builtin_bit_cast(f16x2, r);
}

// round-nearest-even (x * 2^17) for |x*2^17| < 2^22, 2 VALU ops
__device__ __forceinline__ int q17(float x) {
  float r = __builtin_fmaf(x, QSCALE, 12582912.0f);  // 1.5 * 2^23
  return __builtin_bit_cast(int, r) - 0x4B400000;
}

// ---------------------------------------------------------------------------
// setup: blocks [0,512) stats | [512,582) prep | [582,...) xconv.
// ---------------------------------------------------------------------------
__global__ __launch_bounds__(256) void setup_kernel(
    const float* __restrict__ W2, const float* __restrict__ b2,
    const float* __restrict__ W1, const float* __restrict__ x,
    const float* __restrict__ ea, unsigned* __restrict__ Bbuf,
    unsigned* __restrict__ Bw1, unsigned* __restrict__ xh,
    float* __restrict__ gstatsT)
{
  __shared__ float red[4][272];
  const int b = blockIdx.x, tid = threadIdx.x;
  if (b < STAT_GRID) {
    int lane = tid & 63, wave = tid >> 6;
    int nl = lane & 15, q = lane >> 4;
    int gw = b * 4 + wave;
    f32x4 acc = (f32x4){0.f, 0.f, 0.f, 0.f};
    float ms = 0.f;
    for (int c0 = gw; c0 < E_EDGES / 32; c0 += STAT_GRID * 4) {
      const float* p = ea + (size_t)(c0 * 32 + q * 8) * 16 + nl;
      float v0 = p[0],  v1 = p[16], v2 = p[32], v3 = p[48];
      float v4 = p[64], v5 = p[80], v6 = p[96], v7 = p[112];
      ms += (v0 + v1) + (v2 + v3) + (v4 + v5) + (v6 + v7);
      F8U av;
      av.h2[0] = pkrtz(v0, v1); av.h2[1] = pkrtz(v2, v3);
      av.h2[2] = pkrtz(v4, v5); av.h2[3] = pkrtz(v6, v7);
      acc = __builtin_amdgcn_mfma_f32_16x16x32_f16(av.v, av.v, acc, 0, 0, 0);
    }
    ms += __shfl_xor(ms, 16, 64);
    ms += __shfl_xor(ms, 32, 64);
#pragma unroll
    for (int r = 0; r < 4; ++r) red[wave][(q * 4 + r) * 16 + nl] = acc[r];
    if (q == 0) red[wave][256 + nl] = ms;
    __syncthreads();
    for (int v = tid; v < 272; v += 256)
      gstatsT[(size_t)v * STAT_GRID + b] =
          red[0][v] + red[1][v] + red[2][v] + red[3][v];
  } else if (b < STAT_GRID + 70) {
    int idx = (b - STAT_GRID) * 256 + tid;  // [0, 17920) = 16896 + 1024
    if (idx < 33 * 512) {
      int r = idx & 3, lane = (idx >> 2) & 63, nt = (idx >> 8) & 1,
          s = idx >> 9;
      int q = lane >> 4, nl = lane & 15, n = nt * 16 + nl;
      float v0 = 0.f, v1 = 0.f;
      if (n < 20) {
        if (s < 32) {
          int K0 = s * 32 + q * 8 + 2 * r;
          v0 = W2[(K0 >> 4) * 320 + (K0 & 15) * 20 + n];
          v1 = W2[((K0 + 1) >> 4) * 320 + ((K0 + 1) & 15) * 20 + n];
        } else if (q < 2) {
          int i0 = q * 8 + 2 * r;
          v0 = b2[i0 * 20 + n];
          v1 = b2[(i0 + 1) * 20 + n];
        }
      }
      H2U pk; pk.h = pkrtz(v0, v1);
      Bbuf[idx] = pk.u;
    } else {
      int idx2 = idx - 33 * 512;  // [0,1024)
      int r = idx2 & 3, lane = (idx2 >> 2) & 63, nt = idx2 >> 8;
      int q = lane >> 4, nl = lane & 15, n = nt * 16 + nl;
      int k0 = q * 8 + 2 * r;
      float v0 = (k0 < 16)     ? W1[k0 * 64 + n]       : 0.f;
      float v1 = (k0 + 1 < 16) ? W1[(k0 + 1) * 64 + n] : 0.f;
      H2U pk; pk.h = pkrtz(v0, v1);
      Bw1[idx2] = pk.u;
    }
  } else {
    int i = (b - STAT_GRID - 70) * 256 + tid;
    if (i < N_NODES * 8) {
      H2U pk; pk.h = pkrtz(x[2 * i], x[2 * i + 1]);
      xh[i] = pk.u;
    }
  }
}

// ---------------------------------------------------------------------------
// mid: block 64 = stats reduce + BN scale/shift; blocks 0..63 = sumx/cnt.
// Stats reduce: thread-per-row, 4 independent accumulators — keeps 100s
// of loads in flight (R12's wave-per-row shfl chain was 8x slower).
// ---------------------------------------------------------------------------
__global__ __launch_bounds__(256) void mid_kernel(
    const float* __restrict__ gstatsT, const float* __restrict__ W1,
    const float* __restrict__ b1, const float* __restrict__ gamma,
    const float* __restrict__ beta, const float* __restrict__ x,
    const int* __restrict__ batch, float* __restrict__ sc,
    float* __restrict__ sh, float* __restrict__ sumx,
    float* __restrict__ cntf)
{
  const int t = threadIdx.x;
  if (blockIdx.x == G_GRAPHS) {
    __shared__ float S[272];
    for (int v = t; v < 272; v += 256) {
      const float* p = gstatsT + (size_t)v * STAT_GRID;
      float s0 = 0.f, s1 = 0.f, s2 = 0.f, s3 = 0.f;
      for (int bb = 0; bb < STAT_GRID; bb += 4) {
        s0 += p[bb]; s1 += p[bb + 1]; s2 += p[bb + 2]; s3 += p[bb + 3];
      }
      S[v] = (s0 + s1) + (s2 + s3);
    }
    __syncthreads();
    if (t < 64) {
      float w[16];
#pragma unroll
      for (int j = 0; j < 16; ++j) w[j] = W1[j * 64 + t];
      const float invE = 1.0f / (float)E_EDGES;
      float mw = 0.f;
#pragma unroll
      for (int j = 0; j < 16; ++j) mw += S[256 + j] * w[j];
      mw *= invE;
      float qf = 0.f;
      for (int j = 0; j < 16; ++j) {
        float tt = 0.f;
#pragma unroll
        for (int j2 = 0; j2 < 16; ++j2) tt += S[j * 16 + j2] * w[j2];
        qf += w[j] * tt;
      }
      qf *= invE;
      float b = b1[t];
      float meanH = mw + b;
      float eh2 = qf + 2.f * b * mw + b * b;
      float var = eh2 - meanH * meanH;
      float s = gamma[t] * rsqrtf(var + 1e-5f);
      sc[t] = s;
      sh[t] = beta[t] + (b - meanH) * s;
    }
  } else {
    int g = blockIdx.x;
    __shared__ int se[2];
    if (t < 2) {
      int key = g + t;
      int lo = 0, hi = N_NODES;
      while (lo < hi) {
        int mid = (lo + hi) >> 1;
        if (batch[mid] < key) lo = mid + 1; else hi = mid;
      }
      se[t] = lo;
    }
    __syncthreads();
    int start = se[0], end = se[1];
    int c = t & 15, rr = t >> 4;
    float s = 0.f;
    for (int n = start + rr; n < end; n += 16) s += x[(size_t)n * 16 + c];
    __shared__ float red[256];
    red[t] = s;
    __syncthreads();
#pragma unroll
    for (int st = 128; st >= 16; st >>= 1) {
      if (t < st) red[t] += red[t + st];
      __syncthreads();
    }
    if (t < 16) sumx[g * 16 + t] = red[t];
    if (t == 0) cntf[g] = (float)(end - start);
  }
}

// ---------------------------------------------------------------------------
// edge_kernel: R15/R20 byte-exact. 256-thread blocks = 4 waves, wave w =
// K-quarter kq. Shared group data staged once per block in double-
// buffered LDS: wave0 gathers xh(g+1) (issue top, ds_write after K-loop
// = T14), wave2 gathers batch(g+1), wave1 streams ea(g+2); indices
// prefetched 1 group ahead in wave-local regs. Each wave: private bb
// B-table, h-quarter MFMA with deferred hh write, 16(+2)-MFMA K-loop,
// 4 acc chains, LDS int atomics into shared gacc. One barrier per
// iteration. bx (kq==3) lives in LDS.
// ---------------------------------------------------------------------------
__global__ __launch_bounds__(256, 3) void edge_kernel(
    const unsigned* __restrict__ xh, const float* __restrict__ ea,
    const int* __restrict__ ei, const int* __restrict__ batch,
    const float* __restrict__ sc, const float* __restrict__ sh,
    const unsigned* __restrict__ Bbuf, const unsigned* __restrict__ Bw1v,
    int* __restrict__ gpartI)
{
  __shared__ unsigned hh[4][640];   // per-wave h dbuf [w][buf*320 + c*20 + m]
  __shared__ int gacc[1280];        // shared per-graph fixed-point sums
  __shared__ float sEA[2][256];     // [buf][e*16 + f] raw f32 edge_attr
  __shared__ unsigned sXH[2][128];  // [buf][(n*2+half)*4 + word] 32x16B
  __shared__ int sGE[2][16];        // [buf][e] raw batch value
  __shared__ unsigned sBX[2][256];  // bx table (kq==3): [nt][lane*4+word]

  const int tid = threadIdx.x;
  const int w = tid >> 6;           // wave id == kq
  const int lane = tid & 63;
  const int nl = lane & 15, q = lane >> 4;
  const int qh = q & 1;
  const int kq = w;

  for (int v = tid; v < 1280; v += 256) gacc[v] = 0;

  // persistent B fragments (this wave's K-quarter)
  F8U bb[8][2];
#pragma unroll
  for (int sl = 0; sl < 8; ++sl)
#pragma unroll
    for (int nt = 0; nt < 2; ++nt)
      bb[sl][nt].u4 =
          ((const u32x4*)Bbuf)[((kq * 8 + sl) * 2 + nt) * 64 + lane];
  F8U bw1; bw1.u4 = ((const u32x4*)Bw1v)[kq * 64 + lane];
  const float scv = sc[kq * 16 + nl];
  const float shv = sh[kq * 16 + nl];
  const int hrb = (q >> 1) * 20 + nl;  // h read: c = 2sl+(q>>1), m = nl

  if (w == 3) {  // bx -> LDS (saves 8 regs in the uniform allocation)
    u32x4 b0 = ((const u32x4*)Bbuf)[64 * 64 + lane];
    u32x4 b1 = ((const u32x4*)Bbuf)[65 * 64 + lane];
    *(u32x4*)&sBX[0][lane * 4] = b0;
    *(u32x4*)&sBX[1][lane * 4] = b1;
  }

  const int* srcp = ei;
  const int* dstp = ei + E_EDGES;
  int g = blockIdx.x;
  const int g1 = g + GSTRIDE;          // < NGROUPS always (max 6143)
  int srcg = 0, dstg = 0;              // indices for next gather (g+1)

  // ---- prologue: h(g0); stage xh/batch(g0)->buf0, ea(g1)->buf0 ----
  {
    const int base0 = g * 16;
    f32x4 eA = (f32x4){0.f, 0.f, 0.f, 0.f}, eB = eA;
    if (q < 2) {
      const float* p = ea + (size_t)(base0 + nl) * 16 + q * 8;
      eA = *(const f32x4*)p;
      eB = *(const f32x4*)(p + 4);
    }
    F8U aEA;
    if (q < 2) {
      aEA.h2[0] = pkrtz(eA[0], eA[1]); aEA.h2[1] = pkrtz(eA[2], eA[3]);
      aEA.h2[2] = pkrtz(eB[0], eB[1]); aEA.h2[3] = pkrtz(eB[2], eB[3]);
    } else {
      aEA.u4 = (u32x4){0u, 0u, 0u, 0u};
    }
    f32x4 hD = __builtin_amdgcn_mfma_f32_16x16x32_f16(
        aEA.v, bw1.v, (f32x4){0.f, 0.f, 0.f, 0.f}, 0, 0, 0);
    u32x4 hwv;
#pragma unroll
    for (int r = 0; r < 4; ++r) {
      float h = fmaxf(hD[r] * scv + shv, 0.f);
      H2U pk; pk.h = pkrtz(h, h);
      hwv[r] = pk.u;
    }
    *(u32x4*)&hh[w][nl * 20 + q * 4] = hwv;

    if (w == 0) {
      if (lane < 32) {
        int s0 = srcp[base0 + (lane >> 1)];
        u32x4 xv = ((const u32x4*)xh)[s0 * 2 + (lane & 1)];
        *(u32x4*)&sXH[0][lane * 4] = xv;
        srcg = srcp[g1 * 16 + (lane >> 1)];
      }
    } else if (w == 2) {
      if (lane < 16) {
        int d0 = dstp[base0 + lane];
        sGE[0][lane] = batch[d0];
        dstg = dstp[g1 * 16 + lane];
      }
    } else if (w == 1) {
      f32x4 ev = *(const f32x4*)(ea + (size_t)g1 * 256 + lane * 4);
      *(f32x4*)&sEA[0][lane * 4] = ev;
    }
  }
  __syncthreads();

  int cur = 0;
  while (g < NGROUPS) {
    const int gn = g + GSTRIDE, g2 = gn + GSTRIDE;
    const bool hv = (gn < NGROUPS);

    // ---- stage issue (loads only; LDS writes deferred past K-loop) ----
    u32x4 xstg;
    f32x4 estg;
    int gestg = 0, src2 = 0, dst2 = 0;
    if (w == 0) {
      if (lane < 32) {
        if (hv) xstg = ((const u32x4*)xh)[srcg * 2 + (lane & 1)];
        if (g2 < NGROUPS) src2 = srcp[g2 * 16 + (lane >> 1)];
      }
    } else if (w == 2) {
      if (lane < 16) {
        if (hv) gestg = batch[dstg];
        if (g2 < NGROUPS) dst2 = dstp[g2 * 16 + lane];
      }
    } else if (w == 1) {
      if (g2 < NGROUPS)
        estg = *(const f32x4*)(ea + (size_t)g2 * 256 + lane * 4);
    }

    // ---- compute reads (all from LDS staged last iteration) ----
    F8U xcur;
    xcur.u4 = *(const u32x4*)&sXH[cur][(nl * 2 + qh) * 4];
    const int ge0 = sGE[cur][q * 4 + 0] * 20;
    const int ge1 = sGE[cur][q * 4 + 1] * 20;
    const int ge2v = sGE[cur][q * 4 + 2] * 20;
    const int ge3 = sGE[cur][q * 4 + 3] * 20;
    unsigned hu[8];
#pragma unroll
    for (int sl = 0; sl < 8; ++sl) hu[sl] = hh[w][cur * 320 + hrb + sl * 40];

    // ---- h(g+1) MFMA from sEA (LDS write deferred) ----
    f32x4 hDn = (f32x4){0.f, 0.f, 0.f, 0.f};
    if (hv) {
      F8U aEA;
      if (q < 2) {
        f32x4 eA = *(const f32x4*)&sEA[cur][nl * 16 + q * 8];
        f32x4 eB = *(const f32x4*)&sEA[cur][nl * 16 + q * 8 + 4];
        aEA.h2[0] = pkrtz(eA[0], eA[1]); aEA.h2[1] = pkrtz(eA[2], eA[3]);
        aEA.h2[2] = pkrtz(eB[0], eB[1]); aEA.h2[3] = pkrtz(eB[2], eB[3]);
      } else {
        aEA.u4 = (u32x4){0u, 0u, 0u, 0u};
      }
      hDn = __builtin_amdgcn_mfma_f32_16x16x32_f16(
          aEA.v, bw1.v, (f32x4){0.f, 0.f, 0.f, 0.f}, 0, 0, 0);
    }

    // ---- K-loop: A[m][k] = h[m][c] * x[m][i], 4 independent chains ----
    f32x4 a00 = (f32x4){0.f, 0.f, 0.f, 0.f};
    f32x4 a01 = a00, a10 = a00, a11 = a00;
#pragma unroll
    for (int sl = 0; sl < 8; sl += 2) {
      H2U u0; u0.u = hu[sl];
      H2U u1; u1.u = hu[sl + 1];
      F8U av0, av1;
      av0.h2[0] = u0.h * xcur.h2[0];
      av0.h2[1] = u0.h * xcur.h2[1];
      av0.h2[2] = u0.h * xcur.h2[2];
      av0.h2[3] = u0.h * xcur.h2[3];
      av1.h2[0] = u1.h * xcur.h2[0];
      av1.h2[1] = u1.h * xcur.h2[1];
      av1.h2[2] = u1.h * xcur.h2[2];
      av1.h2[3] = u1.h * xcur.h2[3];
      a00 = __builtin_amdgcn_mfma_f32_16x16x32_f16(av0.v, bb[sl][0].v, a00,
                                                   0, 0, 0);
      a10 = __builtin_amdgcn_mfma_f32_16x16x32_f16(av0.v, bb[sl][1].v, a10,
                                                   0, 0, 0);
      a01 = __builtin_amdgcn_mfma_f32_16x16x32_f16(av1.v, bb[sl + 1][0].v,
                                                   a01, 0, 0, 0);
      a11 = __builtin_amdgcn_mfma_f32_16x16x32_f16(av1.v, bb[sl + 1][1].v,
                                                   a11, 0, 0, 0);
    }
    if (kq == 3) {   // b2 extra K-step: A = x, B = bx from LDS
      F8U bxa, bxb;
      bxa.u4 = *(const u32x4*)&sBX[0][lane * 4];
      bxb.u4 = *(const u32x4*)&sBX[1][lane * 4];
      F8U av;
      if (q < 2) av = xcur;
      else       av.u4 = (u32x4){0u, 0u, 0u, 0u};
      a00 = __builtin_amdgcn_mfma_f32_16x16x32_f16(av.v, bxa.v, a00,
                                                   0, 0, 0);
      a10 = __builtin_amdgcn_mfma_f32_16x16x32_f16(av.v, bxb.v, a10,
                                                   0, 0, 0);
    }
    const f32x4 acc0 = a00 + a01;
    const f32x4 acc1 = a10 + a11;

    // ---- deferred writes: hh(g+1) + staging (loads had K-loop cover) ----
    if (hv) {
      u32x4 hwv;
#pragma unroll
      for (int r = 0; r < 4; ++r) {
        float h = fmaxf(hDn[r] * scv + shv, 0.f);
        H2U pk; pk.h = pkrtz(h, h);
        hwv[r] = pk.u;
      }
      *(u32x4*)&hh[w][(cur ^ 1) * 320 + nl * 20 + q * 4] = hwv;
    }
    if (w == 0) {
      if (lane < 32 && hv) *(u32x4*)&sXH[cur ^ 1][lane * 4] = xstg;
    } else if (w == 2) {
      if (lane < 16 && hv) sGE[cur ^ 1][lane] = gestg;
    } else if (w == 1) {
      if (g2 < NGROUPS) *(f32x4*)&sEA[cur ^ 1][lane * 4] = estg;
    }

    // ---- fixed-point partials into shared gacc (native ds atomics) ----
    {
      atomicAdd(&gacc[ge0 + nl], q17(acc0[0]));
      if (nl < 4) atomicAdd(&gacc[ge0 + 16 + nl], q17(acc1[0]));
      atomicAdd(&gacc[ge1 + nl], q17(acc0[1]));
      if (nl < 4) atomicAdd(&gacc[ge1 + 16 + nl], q17(acc1[1]));
      atomicAdd(&gacc[ge2v + nl], q17(acc0[2]));
      if (nl < 4) atomicAdd(&gacc[ge2v + 16 + nl], q17(acc1[2]));
      atomicAdd(&gacc[ge3 + nl], q17(acc0[3]));
      if (nl < 4) atomicAdd(&gacc[ge3 + 16 + nl], q17(acc1[3]));
    }

    __syncthreads();
    g = gn; cur ^= 1;
    srcg = src2; dstg = dst2;
  }

  // ---- flush: global int atomics into super-slice (12 blocks/slice) ----
  const int ssup = blockIdx.x & (NSUP - 1);
  for (int v = tid; v < 1280; v += 256) {
    int gg = v / 20, o = v - gg * 20;
    atomicAdd(&gpartI[(gg * NSUP + ssup) * 20 + o], gacc[v]);
  }
}

// ---------------------------------------------------------------------------
// critic: block per graph. Exact int reduce of 256 super-slices; pooled =
// (msgsum + sumx@root_w + cnt*bias)/max(cnt,1); 2-layer MLP.
// ---------------------------------------------------------------------------
__global__ __launch_bounds__(256) void critic_kernel(
    const int* __restrict__ gpartI, const float* __restrict__ sumx,
    const float* __restrict__ cntf, const float* __restrict__ root_w,
    const float* __restrict__ bias, const float* __restrict__ a,
    const float* __restrict__ Wc1, const float* __restrict__ bc1,
    const float* __restrict__ Wc2, const float* __restrict__ bc2,
    float* __restrict__ out)
{
  int g = blockIdx.x, t = threadIdx.x;
  __shared__ int part[240];
  __shared__ float pooled[20];
  if (t < 240) {
    int col = t % 20, r = t / 20;  // 12 slice groups
    int s = 0;
    const int* gp = gpartI + (size_t)g * NSUP * 20;
    for (int sl = r; sl < NSUP; sl += 12) s += gp[sl * 20 + col];
    part[t] = s;
  }
  __syncthreads();
  if (t < 20) {
    int si = 0;
#pragma unroll
    for (int r = 0; r < 12; ++r) si += part[r * 20 + t];
    float s = (float)si * QINV;
    float cnt = cntf[g];
    float base = bias[t] * cnt;
#pragma unroll
    for (int i = 0; i < 16; ++i) base += sumx[g * 16 + i] * root_w[i * 20 + t];
    pooled[t] = (s + base) / fmaxf(cnt, 1.f);
  }
  __syncthreads();
  float z = bc1[t];
#pragma unroll
  for (int j = 0; j < 20; ++j) z += pooled[j] * Wc1[j * 256 + t];
#pragma unroll
  for (int j = 0; j < 8; ++j) z += a[g * 8 + j] * Wc1[(20 + j) * 256 + t];
  z = fmaxf(z, 0.f);
  float pr = z * Wc2[t];
#pragma unroll
  for (int off = 32; off >= 1; off >>= 1) pr += __shfl_down(pr, off, 64);
  __shared__ float red[4];
  if ((t & 63) == 0) red[t >> 6] = pr;
  __syncthreads();
  if (t == 0) out[g] = red[0] + red[1] + red[2] + red[3] + bc2[0];
}

// ---------------------------------------------------------------------------
extern "C" void kernel_launch(void* const* d_in, const int* in_sizes, int n_in,
                              void* d_out, int out_size, void* d_ws,
                              size_t ws_size, hipStream_t stream) {
  const float* x         = (const float*)d_in[0];
  const float* edge_attr = (const float*)d_in[1];
  const float* a         = (const float*)d_in[2];
  const int*   ei        = (const int*)d_in[3];
  const int*   batch     = (const int*)d_in[4];
  const float* W1        = (const float*)d_in[5];
  const float* b1        = (const float*)d_in[6];
  const float* gamma     = (const float*)d_in[7];
  const float* beta      = (const float*)d_in[8];
  const float* W2        = (const float*)d_in[9];
  const float* b2        = (const float*)d_in[10];
  const float* root_w    = (const float*)d_in[11];
  const float* bias      = (const float*)d_in[12];
  const float* Wc1       = (const float*)d_in[13];
  const float* bc1       = (const float*)d_in[14];
  const float* Wc2       = (const float*)d_in[15];
  const float* bc2       = (const float*)d_in[16];
  float* out = (float*)d_out;

  // ws layout (floats) — gpartI zeroed via memset, rest fully written
  float* wsf     = (float*)d_ws;
  float* sc      = wsf;                 // 64
  float* sh      = wsf + 64;            // 64
  float* sumx    = wsf + 128;           // 1024
  float* cntf    = wsf + 1152;          // 64
  unsigned* Bw1  = (unsigned*)(wsf + 1216);   // 1024 u32
  unsigned* Bbuf = (unsigned*)(wsf + 2240);   // 16896 u32
  float* gstatsT = wsf + 19136;         // 272*512 = 139264
  unsigned* xhp  = (unsigned*)(wsf + 158400); // N*8 = 400000 u32
  int* gpartI    = (int*)(wsf + 558400);      // 64*256*20 = 327680 ints

  (void)hipMemsetAsync(gpartI, 0, (size_t)G_GRAPHS * NSUP * 20 * sizeof(int),
                       stream);

  const int XCONV_BLOCKS = (N_NODES * 8 + 255) / 256;  // 1563
  setup_kernel<<<STAT_GRID + 70 + XCONV_BLOCKS, 256, 0, stream>>>(
      W2, b2, W1, x, edge_attr, Bbuf, Bw1, xhp, gstatsT);
  mid_kernel<<<G_GRAPHS + 1, 256, 0, stream>>>(gstatsT, W1, b1, gamma, beta,
                                               x, batch, sc, sh, sumx, cntf);
  edge_kernel<<<EDGE_GRID, 256, 0, stream>>>(xhp, edge_attr, ei, batch, sc,
                                             sh, Bbuf, Bw1, gpartI);
  critic_kernel<<<G_GRAPHS, 256, 0, stream>>>(gpartI, sumx, cntf, root_w,
                                              bias, a, Wc1, bc1, Wc2, bc2,
                                              out);
}

// Round 13
// 233.398 us; speedup vs baseline: 1.0634x; 1.0165x over previous
//
#include <hip/hip_runtime.h>

// NNConvCritic on MI355X (gfx950).
// R23: dispatch-count probe — the last untouched lever. R20/R22 best
// reproduced 3x (238.4/237.0/237.2us; edge ~100us). Non-edge ~137us
// itemizes to only ~52us of kernel work (mid~25, setup~20, critic~5,
// memset~2) -> ~85us is inter-dispatch gaps/small-dispatch overhead.
// This round: DELETE the hipMemsetAsync dispatch; 320 new setup blocks
// zero gpartI via int4 stores (stream-ordered before edge, NO fences —
// R16's fusion failure was fence-based, this is not). All four kernels'
// existing code paths byte-identical; dispatches 5 -> 4.
// STRUCTURAL CEILING (edge): per-wave K-quarter B-table (64 AGPR) +
// pipeline state ~136 unified regs; 136x4 > 512-reg file -> 3 waves/SIMD
// hard limit. At 3 waves/SIMD every direction tested loses:
//   latency-hiding x3 (R12/R13/R17), fusion (R16), fp atomics (R18),
//   instruction diet x2 (R19), 4-waves x2 (R14/R21 both spill).
// LESSON (R18): fp atomicAdd => CAS retry loop. int fixed-point only.
// LESSON (R16): device-scope atomics+threadfence poison streaming setup.
// LESSON (R12): single-block reduces need MLP, not coalescing.
// Pipeline: setup(+gpartI zero) -> mid -> edge -> critic.

#define E_EDGES   800000
#define N_NODES   50000
#define G_GRAPHS  64
#define EDGE_GRID 3072      // 4-wave blocks
#define NGROUPS   50000     // E/16
#define GSTRIDE   3072      // group streams
#define NSUP      256       // super-slices for the int flush (12 blocks ea)
#define STAT_GRID 512
#define ZERO_BLOCKS 320     // 320 x 1024 ints = 64*256*20 = gpartI size
#define QSCALE    131072.0f // 2^17
#define QINV      (1.0f / 131072.0f)

typedef _Float16 f16x2 __attribute__((ext_vector_type(2)));
typedef _Float16 f16x8 __attribute__((ext_vector_type(8)));
typedef __fp16   fp16x2 __attribute__((ext_vector_type(2)));
typedef float    f32x4 __attribute__((ext_vector_type(4)));
typedef unsigned u32x4 __attribute__((ext_vector_type(4)));
typedef int      i32x4 __attribute__((ext_vector_type(4)));

union H2U { f16x2 h; unsigned u; };
union F8U { f16x8 v; f16x2 h2[4]; u32x4 u4; };

__device__ __forceinline__ f16x2 pkrtz(float a, float b) {
  fp16x2 r = __builtin_amdgcn_cvt_pkrtz(a, b);
  return __builtin_bit_cast(f16x2, r);
}

// round-nearest-even (x * 2^17) for |x*2^17| < 2^22, 2 VALU ops
__device__ __forceinline__ int q17(float x) {
  float r = __builtin_fmaf(x, QSCALE, 12582912.0f);  // 1.5 * 2^23
  return __builtin_bit_cast(int, r) - 0x4B400000;
}

// ---------------------------------------------------------------------------
// setup: [0,512) stats | [512,582) prep | [582, 582+ZB) gpartI zero |
// [582+ZB, ...) xconv.
// ---------------------------------------------------------------------------
__global__ __launch_bounds__(256) void setup_kernel(
    const float* __restrict__ W2, const float* __restrict__ b2,
    const float* __restrict__ W1, const float* __restrict__ x,
    const float* __restrict__ ea, unsigned* __restrict__ Bbuf,
    unsigned* __restrict__ Bw1, unsigned* __restrict__ xh,
    float* __restrict__ gstatsT, int* __restrict__ gpartI)
{
  __shared__ float red[4][272];
  const int b = blockIdx.x, tid = threadIdx.x;
  if (b < STAT_GRID) {
    int lane = tid & 63, wave = tid >> 6;
    int nl = lane & 15, q = lane >> 4;
    int gw = b * 4 + wave;
    f32x4 acc = (f32x4){0.f, 0.f, 0.f, 0.f};
    float ms = 0.f;
    for (int c0 = gw; c0 < E_EDGES / 32; c0 += STAT_GRID * 4) {
      const float* p = ea + (size_t)(c0 * 32 + q * 8) * 16 + nl;
      float v0 = p[0],  v1 = p[16], v2 = p[32], v3 = p[48];
      float v4 = p[64], v5 = p[80], v6 = p[96], v7 = p[112];
      ms += (v0 + v1) + (v2 + v3) + (v4 + v5) + (v6 + v7);
      F8U av;
      av.h2[0] = pkrtz(v0, v1); av.h2[1] = pkrtz(v2, v3);
      av.h2[2] = pkrtz(v4, v5); av.h2[3] = pkrtz(v6, v7);
      acc = __builtin_amdgcn_mfma_f32_16x16x32_f16(av.v, av.v, acc, 0, 0, 0);
    }
    ms += __shfl_xor(ms, 16, 64);
    ms += __shfl_xor(ms, 32, 64);
#pragma unroll
    for (int r = 0; r < 4; ++r) red[wave][(q * 4 + r) * 16 + nl] = acc[r];
    if (q == 0) red[wave][256 + nl] = ms;
    __syncthreads();
    for (int v = tid; v < 272; v += 256)
      gstatsT[(size_t)v * STAT_GRID + b] =
          red[0][v] + red[1][v] + red[2][v] + red[3][v];
  } else if (b < STAT_GRID + 70) {
    int idx = (b - STAT_GRID) * 256 + tid;  // [0, 17920) = 16896 + 1024
    if (idx < 33 * 512) {
      int r = idx & 3, lane = (idx >> 2) & 63, nt = (idx >> 8) & 1,
          s = idx >> 9;
      int q = lane >> 4, nl = lane & 15, n = nt * 16 + nl;
      float v0 = 0.f, v1 = 0.f;
      if (n < 20) {
        if (s < 32) {
          int K0 = s * 32 + q * 8 + 2 * r;
          v0 = W2[(K0 >> 4) * 320 + (K0 & 15) * 20 + n];
          v1 = W2[((K0 + 1) >> 4) * 320 + ((K0 + 1) & 15) * 20 + n];
        } else if (q < 2) {
          int i0 = q * 8 + 2 * r;
          v0 = b2[i0 * 20 + n];
          v1 = b2[(i0 + 1) * 20 + n];
        }
      }
      H2U pk; pk.h = pkrtz(v0, v1);
      Bbuf[idx] = pk.u;
    } else {
      int idx2 = idx - 33 * 512;  // [0,1024)
      int r = idx2 & 3, lane = (idx2 >> 2) & 63, nt = idx2 >> 8;
      int q = lane >> 4, nl = lane & 15, n = nt * 16 + nl;
      int k0 = q * 8 + 2 * r;
      float v0 = (k0 < 16)     ? W1[k0 * 64 + n]       : 0.f;
      float v1 = (k0 + 1 < 16) ? W1[(k0 + 1) * 64 + n] : 0.f;
      H2U pk; pk.h = pkrtz(v0, v1);
      Bw1[idx2] = pk.u;
    }
  } else if (b < STAT_GRID + 70 + ZERO_BLOCKS) {
    // gpartI zero (replaces the hipMemsetAsync dispatch; stream-ordered
    // before edge_kernel — no fence needed)
    int zb = b - (STAT_GRID + 70);
    i32x4 z = (i32x4){0, 0, 0, 0};
    *(i32x4*)&gpartI[(size_t)zb * 1024 + tid * 4] = z;
  } else {
    int i = (b - (STAT_GRID + 70 + ZERO_BLOCKS)) * 256 + tid;
    if (i < N_NODES * 8) {
      H2U pk; pk.h = pkrtz(x[2 * i], x[2 * i + 1]);
      xh[i] = pk.u;
    }
  }
}

// ---------------------------------------------------------------------------
// mid: block 64 = stats reduce + BN scale/shift; blocks 0..63 = sumx/cnt.
// Stats reduce: thread-per-row, 4 independent accumulators — keeps 100s
// of loads in flight (R12's wave-per-row shfl chain was 8x slower).
// ---------------------------------------------------------------------------
__global__ __launch_bounds__(256) void mid_kernel(
    const float* __restrict__ gstatsT, const float* __restrict__ W1,
    const float* __restrict__ b1, const float* __restrict__ gamma,
    const float* __restrict__ beta, const float* __restrict__ x,
    const int* __restrict__ batch, float* __restrict__ sc,
    float* __restrict__ sh, float* __restrict__ sumx,
    float* __restrict__ cntf)
{
  const int t = threadIdx.x;
  if (blockIdx.x == G_GRAPHS) {
    __shared__ float S[272];
    for (int v = t; v < 272; v += 256) {
      const float* p = gstatsT + (size_t)v * STAT_GRID;
      float s0 = 0.f, s1 = 0.f, s2 = 0.f, s3 = 0.f;
      for (int bb = 0; bb < STAT_GRID; bb += 4) {
        s0 += p[bb]; s1 += p[bb + 1]; s2 += p[bb + 2]; s3 += p[bb + 3];
      }
      S[v] = (s0 + s1) + (s2 + s3);
    }
    __syncthreads();
    if (t < 64) {
      float w[16];
#pragma unroll
      for (int j = 0; j < 16; ++j) w[j] = W1[j * 64 + t];
      const float invE = 1.0f / (float)E_EDGES;
      float mw = 0.f;
#pragma unroll
      for (int j = 0; j < 16; ++j) mw += S[256 + j] * w[j];
      mw *= invE;
      float qf = 0.f;
      for (int j = 0; j < 16; ++j) {
        float tt = 0.f;
#pragma unroll
        for (int j2 = 0; j2 < 16; ++j2) tt += S[j * 16 + j2] * w[j2];
        qf += w[j] * tt;
      }
      qf *= invE;
      float b = b1[t];
      float meanH = mw + b;
      float eh2 = qf + 2.f * b * mw + b * b;
      float var = eh2 - meanH * meanH;
      float s = gamma[t] * rsqrtf(var + 1e-5f);
      sc[t] = s;
      sh[t] = beta[t] + (b - meanH) * s;
    }
  } else {
    int g = blockIdx.x;
    __shared__ int se[2];
    if (t < 2) {
      int key = g + t;
      int lo = 0, hi = N_NODES;
      while (lo < hi) {
        int mid = (lo + hi) >> 1;
        if (batch[mid] < key) lo = mid + 1; else hi = mid;
      }
      se[t] = lo;
    }
    __syncthreads();
    int start = se[0], end = se[1];
    int c = t & 15, rr = t >> 4;
    float s = 0.f;
    for (int n = start + rr; n < end; n += 16) s += x[(size_t)n * 16 + c];
    __shared__ float red[256];
    red[t] = s;
    __syncthreads();
#pragma unroll
    for (int st = 128; st >= 16; st >>= 1) {
      if (t < st) red[t] += red[t + st];
      __syncthreads();
    }
    if (t < 16) sumx[g * 16 + t] = red[t];
    if (t == 0) cntf[g] = (float)(end - start);
  }
}

// ---------------------------------------------------------------------------
// edge_kernel: R15/R20/R22 byte-exact. 256-thread blocks = 4 waves, wave
// w = K-quarter kq. Shared group data staged once per block in double-
// buffered LDS: wave0 gathers xh(g+1) (issue top, ds_write after K-loop
// = T14), wave2 gathers batch(g+1), wave1 streams ea(g+2); indices
// prefetched 1 group ahead in wave-local regs. Each wave: private bb
// B-table, h-quarter MFMA with deferred hh write, 16(+2)-MFMA K-loop,
// 4 acc chains, LDS int atomics into shared gacc. One barrier per
// iteration. bx (kq==3) lives in LDS.
// ---------------------------------------------------------------------------
__global__ __launch_bounds__(256, 3) void edge_kernel(
    const unsigned* __restrict__ xh, const float* __restrict__ ea,
    const int* __restrict__ ei, const int* __restrict__ batch,
    const float* __restrict__ sc, const float* __restrict__ sh,
    const unsigned* __restrict__ Bbuf, const unsigned* __restrict__ Bw1v,
    int* __restrict__ gpartI)
{
  __shared__ unsigned hh[4][640];   // per-wave h dbuf [w][buf*320 + c*20 + m]
  __shared__ int gacc[1280];        // shared per-graph fixed-point sums
  __shared__ float sEA[2][256];     // [buf][e*16 + f] raw f32 edge_attr
  __shared__ unsigned sXH[2][128];  // [buf][(n*2+half)*4 + word] 32x16B
  __shared__ int sGE[2][16];        // [buf][e] raw batch value
  __shared__ unsigned sBX[2][256];  // bx table (kq==3): [nt][lane*4+word]

  const int tid = threadIdx.x;
  const int w = tid >> 6;           // wave id == kq
  const int lane = tid & 63;
  const int nl = lane & 15, q = lane >> 4;
  const int qh = q & 1;
  const int kq = w;

  for (int v = tid; v < 1280; v += 256) gacc[v] = 0;

  // persistent B fragments (this wave's K-quarter)
  F8U bb[8][2];
#pragma unroll
  for (int sl = 0; sl < 8; ++sl)
#pragma unroll
    for (int nt = 0; nt < 2; ++nt)
      bb[sl][nt].u4 =
          ((const u32x4*)Bbuf)[((kq * 8 + sl) * 2 + nt) * 64 + lane];
  F8U bw1; bw1.u4 = ((const u32x4*)Bw1v)[kq * 64 + lane];
  const float scv = sc[kq * 16 + nl];
  const float shv = sh[kq * 16 + nl];
  const int hrb = (q >> 1) * 20 + nl;  // h read: c = 2sl+(q>>1), m = nl

  if (w == 3) {  // bx -> LDS (saves 8 regs in the uniform allocation)
    u32x4 b0 = ((const u32x4*)Bbuf)[64 * 64 + lane];
    u32x4 b1 = ((const u32x4*)Bbuf)[65 * 64 + lane];
    *(u32x4*)&sBX[0][lane * 4] = b0;
    *(u32x4*)&sBX[1][lane * 4] = b1;
  }

  const int* srcp = ei;
  const int* dstp = ei + E_EDGES;
  int g = blockIdx.x;
  const int g1 = g + GSTRIDE;          // < NGROUPS always (max 6143)
  int srcg = 0, dstg = 0;              // indices for next gather (g+1)

  // ---- prologue: h(g0); stage xh/batch(g0)->buf0, ea(g1)->buf0 ----
  {
    const int base0 = g * 16;
    f32x4 eA = (f32x4){0.f, 0.f, 0.f, 0.f}, eB = eA;
    if (q < 2) {
      const float* p = ea + (size_t)(base0 + nl) * 16 + q * 8;
      eA = *(const f32x4*)p;
      eB = *(const f32x4*)(p + 4);
    }
    F8U aEA;
    if (q < 2) {
      aEA.h2[0] = pkrtz(eA[0], eA[1]); aEA.h2[1] = pkrtz(eA[2], eA[3]);
      aEA.h2[2] = pkrtz(eB[0], eB[1]); aEA.h2[3] = pkrtz(eB[2], eB[3]);
    } else {
      aEA.u4 = (u32x4){0u, 0u, 0u, 0u};
    }
    f32x4 hD = __builtin_amdgcn_mfma_f32_16x16x32_f16(
        aEA.v, bw1.v, (f32x4){0.f, 0.f, 0.f, 0.f}, 0, 0, 0);
    u32x4 hwv;
#pragma unroll
    for (int r = 0; r < 4; ++r) {
      float h = fmaxf(hD[r] * scv + shv, 0.f);
      H2U pk; pk.h = pkrtz(h, h);
      hwv[r] = pk.u;
    }
    *(u32x4*)&hh[w][nl * 20 + q * 4] = hwv;

    if (w == 0) {
      if (lane < 32) {
        int s0 = srcp[base0 + (lane >> 1)];
        u32x4 xv = ((const u32x4*)xh)[s0 * 2 + (lane & 1)];
        *(u32x4*)&sXH[0][lane * 4] = xv;
        srcg = srcp[g1 * 16 + (lane >> 1)];
      }
    } else if (w == 2) {
      if (lane < 16) {
        int d0 = dstp[base0 + lane];
        sGE[0][lane] = batch[d0];
        dstg = dstp[g1 * 16 + lane];
      }
    } else if (w == 1) {
      f32x4 ev = *(const f32x4*)(ea + (size_t)g1 * 256 + lane * 4);
      *(f32x4*)&sEA[0][lane * 4] = ev;
    }
  }
  __syncthreads();

  int cur = 0;
  while (g < NGROUPS) {
    const int gn = g + GSTRIDE, g2 = gn + GSTRIDE;
    const bool hv = (gn < NGROUPS);

    // ---- stage issue (loads only; LDS writes deferred past K-loop) ----
    u32x4 xstg;
    f32x4 estg;
    int gestg = 0, src2 = 0, dst2 = 0;
    if (w == 0) {
      if (lane < 32) {
        if (hv) xstg = ((const u32x4*)xh)[srcg * 2 + (lane & 1)];
        if (g2 < NGROUPS) src2 = srcp[g2 * 16 + (lane >> 1)];
      }
    } else if (w == 2) {
      if (lane < 16) {
        if (hv) gestg = batch[dstg];
        if (g2 < NGROUPS) dst2 = dstp[g2 * 16 + lane];
      }
    } else if (w == 1) {
      if (g2 < NGROUPS)
        estg = *(const f32x4*)(ea + (size_t)g2 * 256 + lane * 4);
    }

    // ---- compute reads (all from LDS staged last iteration) ----
    F8U xcur;
    xcur.u4 = *(const u32x4*)&sXH[cur][(nl * 2 + qh) * 4];
    const int ge0 = sGE[cur][q * 4 + 0] * 20;
    const int ge1 = sGE[cur][q * 4 + 1] * 20;
    const int ge2v = sGE[cur][q * 4 + 2] * 20;
    const int ge3 = sGE[cur][q * 4 + 3] * 20;
    unsigned hu[8];
#pragma unroll
    for (int sl = 0; sl < 8; ++sl) hu[sl] = hh[w][cur * 320 + hrb + sl * 40];

    // ---- h(g+1) MFMA from sEA (LDS write deferred) ----
    f32x4 hDn = (f32x4){0.f, 0.f, 0.f, 0.f};
    if (hv) {
      F8U aEA;
      if (q < 2) {
        f32x4 eA = *(const f32x4*)&sEA[cur][nl * 16 + q * 8];
        f32x4 eB = *(const f32x4*)&sEA[cur][nl * 16 + q * 8 + 4];
        aEA.h2[0] = pkrtz(eA[0], eA[1]); aEA.h2[1] = pkrtz(eA[2], eA[3]);
        aEA.h2[2] = pkrtz(eB[0], eB[1]); aEA.h2[3] = pkrtz(eB[2], eB[3]);
      } else {
        aEA.u4 = (u32x4){0u, 0u, 0u, 0u};
      }
      hDn = __builtin_amdgcn_mfma_f32_16x16x32_f16(
          aEA.v, bw1.v, (f32x4){0.f, 0.f, 0.f, 0.f}, 0, 0, 0);
    }

    // ---- K-loop: A[m][k] = h[m][c] * x[m][i], 4 independent chains ----
    f32x4 a00 = (f32x4){0.f, 0.f, 0.f, 0.f};
    f32x4 a01 = a00, a10 = a00, a11 = a00;
#pragma unroll
    for (int sl = 0; sl < 8; sl += 2) {
      H2U u0; u0.u = hu[sl];
      H2U u1; u1.u = hu[sl + 1];
      F8U av0, av1;
      av0.h2[0] = u0.h * xcur.h2[0];
      av0.h2[1] = u0.h * xcur.h2[1];
      av0.h2[2] = u0.h * xcur.h2[2];
      av0.h2[3] = u0.h * xcur.h2[3];
      av1.h2[0] = u1.h * xcur.h2[0];
      av1.h2[1] = u1.h * xcur.h2[1];
      av1.h2[2] = u1.h * xcur.h2[2];
      av1.h2[3] = u1.h * xcur.h2[3];
      a00 = __builtin_amdgcn_mfma_f32_16x16x32_f16(av0.v, bb[sl][0].v, a00,
                                                   0, 0, 0);
      a10 = __builtin_amdgcn_mfma_f32_16x16x32_f16(av0.v, bb[sl][1].v, a10,
                                                   0, 0, 0);
      a01 = __builtin_amdgcn_mfma_f32_16x16x32_f16(av1.v, bb[sl + 1][0].v,
                                                   a01, 0, 0, 0);
      a11 = __builtin_amdgcn_mfma_f32_16x16x32_f16(av1.v, bb[sl + 1][1].v,
                                                   a11, 0, 0, 0);
    }
    if (kq == 3) {   // b2 extra K-step: A = x, B = bx from LDS
      F8U bxa, bxb;
      bxa.u4 = *(const u32x4*)&sBX[0][lane * 4];
      bxb.u4 = *(const u32x4*)&sBX[1][lane * 4];
      F8U av;
      if (q < 2) av = xcur;
      else       av.u4 = (u32x4){0u, 0u, 0u, 0u};
      a00 = __builtin_amdgcn_mfma_f32_16x16x32_f16(av.v, bxa.v, a00,
                                                   0, 0, 0);
      a10 = __builtin_amdgcn_mfma_f32_16x16x32_f16(av.v, bxb.v, a10,
                                                   0, 0, 0);
    }
    const f32x4 acc0 = a00 + a01;
    const f32x4 acc1 = a10 + a11;

    // ---- deferred writes: hh(g+1) + staging (loads had K-loop cover) ----
    if (hv) {
      u32x4 hwv;
#pragma unroll
      for (int r = 0; r < 4; ++r) {
        float h = fmaxf(hDn[r] * scv + shv, 0.f);
        H2U pk; pk.h = pkrtz(h, h);
        hwv[r] = pk.u;
      }
      *(u32x4*)&hh[w][(cur ^ 1) * 320 + nl * 20 + q * 4] = hwv;
    }
    if (w == 0) {
      if (lane < 32 && hv) *(u32x4*)&sXH[cur ^ 1][lane * 4] = xstg;
    } else if (w == 2) {
      if (lane < 16 && hv) sGE[cur ^ 1][lane] = gestg;
    } else if (w == 1) {
      if (g2 < NGROUPS) *(f32x4*)&sEA[cur ^ 1][lane * 4] = estg;
    }

    // ---- fixed-point partials into shared gacc (native ds atomics) ----
    {
      atomicAdd(&gacc[ge0 + nl], q17(acc0[0]));
      if (nl < 4) atomicAdd(&gacc[ge0 + 16 + nl], q17(acc1[0]));
      atomicAdd(&gacc[ge1 + nl], q17(acc0[1]));
      if (nl < 4) atomicAdd(&gacc[ge1 + 16 + nl], q17(acc1[1]));
      atomicAdd(&gacc[ge2v + nl], q17(acc0[2]));
      if (nl < 4) atomicAdd(&gacc[ge2v + 16 + nl], q17(acc1[2]));
      atomicAdd(&gacc[ge3 + nl], q17(acc0[3]));
      if (nl < 4) atomicAdd(&gacc[ge3 + 16 + nl], q17(acc1[3]));
    }

    __syncthreads();
    g = gn; cur ^= 1;
    srcg = src2; dstg = dst2;
  }

  // ---- flush: global int atomics into super-slice (12 blocks/slice) ----
  const int ssup = blockIdx.x & (NSUP - 1);
  for (int v = tid; v < 1280; v += 256) {
    int gg = v / 20, o = v - gg * 20;
    atomicAdd(&gpartI[(gg * NSUP + ssup) * 20 + o], gacc[v]);
  }
}

// ---------------------------------------------------------------------------
// critic: block per graph. Exact int reduce of 256 super-slices; pooled =
// (msgsum + sumx@root_w + cnt*bias)/max(cnt,1); 2-layer MLP.
// ---------------------------------------------------------------------------
__global__ __launch_bounds__(256) void critic_kernel(
    const int* __restrict__ gpartI, const float* __restrict__ sumx,
    const float* __restrict__ cntf, const float* __restrict__ root_w,
    const float* __restrict__ bias, const float* __restrict__ a,
    const float* __restrict__ Wc1, const float* __restrict__ bc1,
    const float* __restrict__ Wc2, const float* __restrict__ bc2,
    float* __restrict__ out)
{
  int g = blockIdx.x, t = threadIdx.x;
  __shared__ int part[240];
  __shared__ float pooled[20];
  if (t < 240) {
    int col = t % 20, r = t / 20;  // 12 slice groups
    int s = 0;
    const int* gp = gpartI + (size_t)g * NSUP * 20;
    for (int sl = r; sl < NSUP; sl += 12) s += gp[sl * 20 + col];
    part[t] = s;
  }
  __syncthreads();
  if (t < 20) {
    int si = 0;
#pragma unroll
    for (int r = 0; r < 12; ++r) si += part[r * 20 + t];
    float s = (float)si * QINV;
    float cnt = cntf[g];
    float base = bias[t] * cnt;
#pragma unroll
    for (int i = 0; i < 16; ++i) base += sumx[g * 16 + i] * root_w[i * 20 + t];
    pooled[t] = (s + base) / fmaxf(cnt, 1.f);
  }
  __syncthreads();
  float z = bc1[t];
#pragma unroll
  for (int j = 0; j < 20; ++j) z += pooled[j] * Wc1[j * 256 + t];
#pragma unroll
  for (int j = 0; j < 8; ++j) z += a[g * 8 + j] * Wc1[(20 + j) * 256 + t];
  z = fmaxf(z, 0.f);
  float pr = z * Wc2[t];
#pragma unroll
  for (int off = 32; off >= 1; off >>= 1) pr += __shfl_down(pr, off, 64);
  __shared__ float red[4];
  if ((t & 63) == 0) red[t >> 6] = pr;
  __syncthreads();
  if (t == 0) out[g] = red[0] + red[1] + red[2] + red[3] + bc2[0];
}

// ---------------------------------------------------------------------------
extern "C" void kernel_launch(void* const* d_in, const int* in_sizes, int n_in,
                              void* d_out, int out_size, void* d_ws,
                              size_t ws_size, hipStream_t stream) {
  const float* x         = (const float*)d_in[0];
  const float* edge_attr = (const float*)d_in[1];
  const float* a         = (const float*)d_in[2];
  const int*   ei        = (const int*)d_in[3];
  const int*   batch     = (const int*)d_in[4];
  const float* W1        = (const float*)d_in[5];
  const float* b1        = (const float*)d_in[6];
  const float* gamma     = (const float*)d_in[7];
  const float* beta      = (const float*)d_in[8];
  const float* W2        = (const float*)d_in[9];
  const float* b2        = (const float*)d_in[10];
  const float* root_w    = (const float*)d_in[11];
  const float* bias      = (const float*)d_in[12];
  const float* Wc1       = (const float*)d_in[13];
  const float* bc1       = (const float*)d_in[14];
  const float* Wc2       = (const float*)d_in[15];
  const float* bc2       = (const float*)d_in[16];
  float* out = (float*)d_out;

  // ws layout (floats) — gpartI zeroed by setup's ZERO_BLOCKS section
  float* wsf     = (float*)d_ws;
  float* sc      = wsf;                 // 64
  float* sh      = wsf + 64;            // 64
  float* sumx    = wsf + 128;           // 1024
  float* cntf    = wsf + 1152;          // 64
  unsigned* Bw1  = (unsigned*)(wsf + 1216);   // 1024 u32
  unsigned* Bbuf = (unsigned*)(wsf + 2240);   // 16896 u32
  float* gstatsT = wsf + 19136;         // 272*512 = 139264
  unsigned* xhp  = (unsigned*)(wsf + 158400); // N*8 = 400000 u32
  int* gpartI    = (int*)(wsf + 558400);      // 64*256*20 = 327680 ints

  const int XCONV_BLOCKS = (N_NODES * 8 + 255) / 256;  // 1563
  setup_kernel<<<STAT_GRID + 70 + ZERO_BLOCKS + XCONV_BLOCKS, 256, 0,
                 stream>>>(W2, b2, W1, x, edge_attr, Bbuf, Bw1, xhp,
                           gstatsT, gpartI);
  mid_kernel<<<G_GRAPHS + 1, 256, 0, stream>>>(gstatsT, W1, b1, gamma, beta,
                                               x, batch, sc, sh, sumx, cntf);
  edge_kernel<<<EDGE_GRID, 256, 0, stream>>>(xhp, edge_attr, ei, batch, sc,
                                             sh, Bbuf, Bw1, gpartI);
  critic_kernel<<<G_GRAPHS, 256, 0, stream>>>(gpartI, sumx, cntf, root_w,
                                              bias, a, Wc1, bc1, Wc2, bc2,
                                              out);
}